// Round 9
// baseline (553.966 us; speedup 1.0000x reference)
//
#include <hip/hip_runtime.h>

// GNNML3 forward. R13: re-fuse aggregate+transform at 32-node tiles (k_layer32).
// R8's 64-node fusion failed on concurrency (42KB LDS -> 3 blk/CU, 782 blocks, 36% occ),
// not on the traffic idea. 32-node tile: 21KB LDS -> 7 blk/CU (28 waves), 1563 blocks.
// Phase1: wave w aggregates nodes w*8..w*8+7 (EDGE math bit-identical) into LDS A-tile.
// Phase2: wave w = col-tile w; 2 row-accs x 10 ksteps x (hi,lo) = 40 MFMA, same
// accumulation order as split version. Kills 64MB/layer agg roundtrip + 4 launches.

#define Nn   50000
#define Ne   1600000
#define Gg   128
#define NEk  5
#define NINf 16
#define NCLSo 6
#define NB   196        // ceil((Nn+1)/256)
#define RBK  128        // rank histogram blocks
#define CHK  (Ne / RBK) // 12500 edges per block (exact)

using short8 = __attribute__((ext_vector_type(8))) short;
using f32x4  = __attribute__((ext_vector_type(4))) float;
using f32x2  = __attribute__((ext_vector_type(2))) float;
using uint4v = __attribute__((ext_vector_type(4))) unsigned;  // native vec for nt-store

__device__ __forceinline__ float2 bf2u(unsigned u) {
    return make_float2(__uint_as_float(u << 16), __uint_as_float(u & 0xffff0000u));
}
__device__ __forceinline__ unsigned f2bf(float a, float b) {
    unsigned ua = __float_as_uint(a), ub = __float_as_uint(b);
    ua += 0x7fffu + ((ua >> 16) & 1u);
    ub += 0x7fffu + ((ub >> 16) & 1u);
    return (ua >> 16) | (ub & 0xffff0000u);
}
__device__ __forceinline__ unsigned short f2bf1(float a) {
    unsigned ua = __float_as_uint(a);
    ua += 0x7fffu + ((ua >> 16) & 1u);
    return (unsigned short)(ua >> 16);
}

// packed 2xf32 fma with splat multiplier (backend: v_pk_fma_f32).
__device__ __forceinline__ f32x2 fma2s(float a, f32x2 x, f32x2 c) {
#if __has_builtin(__builtin_elementwise_fma)
    f32x2 av; av.x = a; av.y = a;
    return __builtin_elementwise_fma(av, x, c);
#else
    c.x = fmaf(a, x.x, c.x); c.y = fmaf(a, x.y, c.y);
    return c;
#endif
}

// ---------------- prep kernels ----------------

// x [Nn][16] fp32 -> h0 [Nn][32] uint (bf16x2 pairs, features >=16 zero)
__global__ void k_pad_x(const float* __restrict__ x, unsigned* __restrict__ h0) {
    int i = blockIdx.x * 256 + threadIdx.x;           // over Nn*32
    if (i >= Nn * 32) return;
    int n = i >> 5, p = i & 31;
    int f0 = 2 * p;
    float v0 = (f0 < NINf) ? x[n * NINf + f0] : 0.f;
    float v1 = (f0 + 1 < NINf) ? x[n * NINf + f0 + 1] : 0.f;
    h0[i] = f2bf(v0, v1);
}

__global__ void k_pad_w1(const float* __restrict__ W1, float* __restrict__ W1p) {
    int i = blockIdx.x * 256 + threadIdx.x;           // over 5*64*64
    if (i >= NEk * 64 * 64) return;
    int h = i & 63, f = (i >> 6) & 63, k = i >> 12;
    W1p[i] = (f < NINf) ? W1[(k * NINf + f) * 64 + h] : 0.f;
}

// pack W[320][64] fp32 into MFMA B-fragment layout, split hi/lo bf16.
// layout index: ((nt*10 + kstep)*64 + lane)*8 + j ; k = kstep*32 + (lane>>4)*8 + j,
// col = nt*16 + (lane&15).  20480 elements per layer.
__global__ void k_pack_b(const float* __restrict__ W, unsigned short* __restrict__ bhi,
                         unsigned short* __restrict__ blo) {
    int i = blockIdx.x * 256 + threadIdx.x;
    if (i >= 20480) return;
    int j = i & 7, lane = (i >> 3) & 63, t2 = i >> 9;   // t2 = nt*10+kstep, 0..39
    int nt = t2 / 10, kstep = t2 - nt * 10;
    int k = kstep * 32 + (lane >> 4) * 8 + j;
    int col = nt * 16 + (lane & 15);
    float v = W[k * 64 + col];
    unsigned short hi = f2bf1(v);
    float fhi = __uint_as_float(((unsigned)hi) << 16);
    bhi[i] = hi;
    blo[i] = f2bf1(v - fhi);
}

// LDS-privatized per-block histogram + local rank, single pass, u8x4-packed counts.
__global__ __launch_bounds__(1024) void k_rankhist(
    const int* __restrict__ ei, unsigned short* __restrict__ lrank,
    unsigned short* __restrict__ cnt /* [RBK][Nn] u16 */) {
    __shared__ unsigned hist[12500];                  // 50 KB: 4 u8 counts per word
    int b = blockIdx.x, t = threadIdx.x;
    int e0 = b * CHK;
    for (int w = t; w < 12500; w += 1024) hist[w] = 0;
    __syncthreads();
    for (int i = t; i < CHK; i += 1024) {
        int d = ei[Ne + e0 + i];
        unsigned sh = 8u * (unsigned)(d & 3);
        unsigned old = atomicAdd(&hist[d >> 2], 1u << sh);
        lrank[e0 + i] = (unsigned short)((old >> sh) & 0xffu);
    }
    __syncthreads();
    unsigned* co = (unsigned*)(cnt + (size_t)b * Nn);  // 4B-aligned (Nn even)
    for (int w = t; w < 12500; w += 1024) {
        unsigned hv = hist[w];
        co[2 * w]     = (hv & 0xffu) | ((hv >> 8) & 0xffu) << 16;
        co[2 * w + 1] = ((hv >> 16) & 0xffu) | (hv >> 24) << 16;
    }
}

// per-node exclusive scan over the RBK block counts (in place) + total deg.
__global__ void k_colscan(unsigned short* __restrict__ cnt, int* __restrict__ deg) {
    int d = blockIdx.x * 256 + threadIdx.x;
    if (d >= Nn) return;
    int s = 0;
#pragma unroll 4
    for (int b = 0; b < RBK; ++b) {
        int t = cnt[(size_t)b * Nn + d];
        cnt[(size_t)b * Nn + d] = (unsigned short)s;   // deg(d) ~<=100, fits u16
        s += t;
    }
    deg[d] = s;
}

// -------- 3-phase exclusive scan of deg[0..Nn] -> rowstart --------

__global__ void k_blocksum(const int* __restrict__ deg, int* __restrict__ bsum) {
    __shared__ int l[256];
    int t = threadIdx.x;
    int i = blockIdx.x * 256 + t;
    l[t] = (i < Nn) ? deg[i] : 0;
    __syncthreads();
    for (int off = 128; off > 0; off >>= 1) {
        if (t < off) l[t] += l[t + off];
        __syncthreads();
    }
    if (t == 0) bsum[blockIdx.x] = l[0];
}

__global__ void k_scanpart(const int* __restrict__ bsum, int* __restrict__ boff) {
    __shared__ int l[256];
    int t = threadIdx.x;
    int v = (t < NB) ? bsum[t] : 0;
    l[t] = v;
    __syncthreads();
    for (int off = 1; off < 256; off <<= 1) {
        int u = (t >= off) ? l[t - off] : 0;
        __syncthreads();
        l[t] += u;
        __syncthreads();
    }
    if (t < NB) boff[t] = l[t] - v;                   // exclusive
}

__global__ void k_scanfinal(const int* __restrict__ deg, const int* __restrict__ boff,
                            int* __restrict__ rowstart) {
    __shared__ int l[256];
    int t = threadIdx.x;
    int i = blockIdx.x * 256 + t;
    int v = (i < Nn) ? deg[i] : 0;
    l[t] = v;
    __syncthreads();
    for (int off = 1; off < 256; off <<= 1) {
        int u = (t >= off) ? l[t - off] : 0;
        __syncthreads();
        l[t] += u;
        __syncthreads();
    }
    if (i <= Nn) rowstart[i] = boff[blockIdx.x] + l[t] - v;
}

// deterministic placement, 4 edges/thread, nontemporal 16B scatter stores.
__global__ __launch_bounds__(256) void k_place(
    const int* __restrict__ ei, const float* __restrict__ eattr,
    const int* __restrict__ rowstart,
    const unsigned short* __restrict__ lrank,
    const unsigned short* __restrict__ cnt,
    unsigned* __restrict__ recs /* uint4 records, word view */) {
    int e = (blockIdx.x * 256 + threadIdx.x) * 4;
    if (e >= Ne) return;
    int b = e / CHK;                                   // uniform over the 4-edge group
    const unsigned short* cb = cnt + (size_t)b * Nn;

    int4 dv = *(const int4*)(ei + Ne + e);
    int4 sv = *(const int4*)(ei + e);
    ushort4 lr = *(const ushort4*)(lrank + e);
    union { float4 v4[5]; float f[20]; } a;
#pragma unroll
    for (int q = 0; q < 5; ++q) a.v4[q] = *(const float4*)(eattr + (size_t)e * 5 + q * 4);

    int d[4] = { dv.x, dv.y, dv.z, dv.w };
    int s[4] = { sv.x, sv.y, sv.z, sv.w };
    unsigned short r4[4] = { lr.x, lr.y, lr.z, lr.w };
    int pos[4];
#pragma unroll
    for (int j = 0; j < 4; ++j)
        pos[j] = rowstart[d[j]] + cb[d[j]] + r4[j];    // 4 independent L2-gather chains
#pragma unroll
    for (int j = 0; j < 4; ++j) {
        uint4v rr;
        rr.x = (unsigned)s[j];
        rr.y = f2bf(a.f[5 * j],     a.f[5 * j + 1]);
        rr.z = f2bf(a.f[5 * j + 2], a.f[5 * j + 3]);
        rr.w = f2bf(a.f[5 * j + 4], 0.f);
        __builtin_nontemporal_store(rr, (uint4v*)(recs + (size_t)pos[j] * 4));
    }
}

// batch is sorted -> segment bounds by boundary detection
__global__ void k_bounds(const int* __restrict__ batch, int* __restrict__ sg,
                         int* __restrict__ eg) {
    int n = blockIdx.x * 256 + threadIdx.x;
    if (n >= Nn) return;
    int g = batch[n];
    if (n == 0) sg[g] = 0;
    else {
        int gp = batch[n - 1];
        if (gp != g) { sg[g] = n; eg[gp] = n; }
    }
    if (n == Nn - 1) eg[g] = Nn;
}

// ---------------- fused layer kernel (32-node tile) ----------------
// Block: 256 thr = 4 waves, 32 nodes, LDS 32*SPAD uint4 = 20992 B -> 7 blocks/CU.
// Phase 1: wave w aggregates nodes w*8..w*8+7 into LDS A-tile (EDGE math identical
// to split k_aggregate). Phase 2: wave w = column-tile w (cols w*16..+15); acc0 =
// rows 0-15, acc1 = rows 16-31; 10 ksteps x (hi,lo) per acc = 40 MFMA, accumulation
// order identical to split k_transform. Phase 3: C-spill to LDS fp32 [32][72], pack.
#define SPAD 41
__global__ __launch_bounds__(256) void k_layer32(
    const unsigned* __restrict__ hin, const int* __restrict__ rowstart,
    const uint4* __restrict__ recs, const unsigned short* __restrict__ bhi,
    const unsigned short* __restrict__ blo, const float* __restrict__ bias,
    unsigned* __restrict__ outh) {
    __shared__ uint4 smem[32 * SPAD];                  // 20992 B
    unsigned* aggw = (unsigned*)smem;                  // word view: row*164 + ch*32 + l
    int t = threadIdx.x;
    int lane = t & 63, wave = t >> 6;
    int l = lane & 31, half = lane >> 5;
    int blk = blockIdx.x;

    // ---- phase 1: aggregate 8 nodes per wave into LDS A-tile ----
#pragma unroll 1
    for (int ni = 0; ni < 8; ++ni) {
        int row = wave * 8 + ni;
        int node = blk * 32 + row;
        if (node >= Nn) node = Nn - 1;                 // tail: redundant work, rows defined
        node = __builtin_amdgcn_readfirstlane(node);
        int beg = rowstart[node], end = rowstart[node + 1];
        f32x2 c0 = {0.f, 0.f}, c1 = c0, c2 = c0, c3 = c0, c4 = c0;
        int ee = beg;
#define EDGE(E) { \
    uint4 r = recs[(E)]; \
    unsigned hx = hin[(size_t)(int)r.x * 32 + l]; \
    f32x2 xv; xv.x = __uint_as_float(hx << 16); xv.y = __uint_as_float(hx & 0xffff0000u); \
    float A0 = __uint_as_float(r.y << 16), A1 = __uint_as_float(r.y & 0xffff0000u); \
    float A2 = __uint_as_float(r.z << 16), A3 = __uint_as_float(r.z & 0xffff0000u); \
    float A4 = __uint_as_float(r.w << 16); \
    c0 = fma2s(A0, xv, c0); c1 = fma2s(A1, xv, c1); \
    c2 = fma2s(A2, xv, c2); c3 = fma2s(A3, xv, c3); \
    c4 = fma2s(A4, xv, c4); }
        for (; ee + 8 <= end; ee += 8) {
            EDGE(ee + half) EDGE(ee + 2 + half) EDGE(ee + 4 + half) EDGE(ee + 6 + half)
        }
        for (; ee + 2 <= end; ee += 2) { EDGE(ee + half) }
        if (ee < end) { if (half == 0) { EDGE(ee) } }
#undef EDGE
        // fold half 1 into half 0
        c0.x += __shfl(c0.x, lane ^ 32); c0.y += __shfl(c0.y, lane ^ 32);
        c1.x += __shfl(c1.x, lane ^ 32); c1.y += __shfl(c1.y, lane ^ 32);
        c2.x += __shfl(c2.x, lane ^ 32); c2.y += __shfl(c2.y, lane ^ 32);
        c3.x += __shfl(c3.x, lane ^ 32); c3.y += __shfl(c3.y, lane ^ 32);
        c4.x += __shfl(c4.x, lane ^ 32); c4.y += __shfl(c4.y, lane ^ 32);
        if (half == 0) {
            unsigned* o = aggw + row * (SPAD * 4) + l;  // lanes 0..31 -> banks 0..31
            o[0]   = f2bf(c0.x, c0.y);
            o[32]  = f2bf(c1.x, c1.y);
            o[64]  = f2bf(c2.x, c2.y);
            o[96]  = f2bf(c3.x, c3.y);
            o[128] = f2bf(c4.x, c4.y);
        }
    }
    __syncthreads();

    // ---- phase 2: MFMA from LDS; wave w = col-tile w ----
    int m = lane & 15, quad = lane >> 4;
    f32x4 acc0 = {0.f, 0.f, 0.f, 0.f}, acc1 = acc0;
    const uint4* ar0 = smem + m * SPAD + quad;         // rows 0-15
    const uint4* ar1 = smem + (16 + m) * SPAD + quad;  // rows 16-31
    const size_t bbase = (size_t)wave * 5120;          // nt = wave
#pragma unroll 2
    for (int ks = 0; ks < 10; ++ks) {
        short8 a0 = *(const short8*)(ar0 + ks * 4);
        short8 a1 = *(const short8*)(ar1 + ks * 4);
        size_t bb = bbase + ((size_t)ks * 64 + lane) * 8;
        short8 h = *(const short8*)(bhi + bb);
        short8 lo = *(const short8*)(blo + bb);
        acc0 = __builtin_amdgcn_mfma_f32_16x16x32_bf16(a0, h,  acc0, 0, 0, 0);
        acc0 = __builtin_amdgcn_mfma_f32_16x16x32_bf16(a0, lo, acc0, 0, 0, 0);
        acc1 = __builtin_amdgcn_mfma_f32_16x16x32_bf16(a1, h,  acc1, 0, 0, 0);
        acc1 = __builtin_amdgcn_mfma_f32_16x16x32_bf16(a1, lo, acc1, 0, 0, 0);
    }
    __syncthreads();                                   // all waves done reading A

    // ---- phase 3: C-spill [32 rows][72] fp32, then pack ----
    // C layout (16x16x32): col=lane&15 (global col = wave*16+m), row=quad*4+reg.
    float* Cs = (float*)smem;
#pragma unroll
    for (int r = 0; r < 4; ++r) {
        int base = (quad * 4 + r) * 72 + wave * 16 + m;
        Cs[base]            = acc0[r];
        Cs[base + 16 * 72]  = acc1[r];
    }
    __syncthreads();

    // pack: row = t>>3 (0..31), grp = t&7 -> 4 bf16-pair slots (one uint4)
    {
        int row = t >> 3, grp = t & 7;
        int node = blk * 32 + row;
        if (node < Nn) {
            const float* cr = Cs + row * 72;
            unsigned o[4];
#pragma unroll
            for (int j = 0; j < 4; ++j) {
                int pp = grp * 4 + j;
                float v0 = fmaxf(cr[2 * pp]     + bias[2 * pp],     0.f);
                float v1 = fmaxf(cr[2 * pp + 1] + bias[2 * pp + 1], 0.f);
                o[j] = f2bf(v0, v1);
            }
            *(uint4*)(outh + (size_t)node * 32 + grp * 4) =
                make_uint4(o[0], o[1], o[2], o[3]);
        }
    }
}

// ---------------- pooling + head ----------------

__global__ __launch_bounds__(256) void k_pool(const unsigned* __restrict__ h,
                                              const int* __restrict__ sg,
                                              const int* __restrict__ eg,
                                              float* __restrict__ pooled) {
    __shared__ float2 ls[256], lm[256];
    int g = blockIdx.x, t = threadIdx.x;
    int p = t & 31, q = t >> 5;                        // 32 feature-pairs x 8 node-strides
    int s = sg[g], e = eg[g];
    float2 sum = {0.f, 0.f}, mx = {0.f, 0.f};          // relu>=0 -> 0 valid max identity
    for (int n = s + q; n < e; n += 8) {
        float2 v = bf2u(h[(size_t)n * 32 + p]);
        sum.x += v.x; sum.y += v.y;
        mx.x = fmaxf(mx.x, v.x); mx.y = fmaxf(mx.y, v.y);
    }
    ls[t] = sum; lm[t] = mx;
    __syncthreads();
    if (t < 32) {
        float2 ss = ls[t], mm = lm[t];
        for (int i = 1; i < 8; ++i) {
            float2 a = ls[t + i * 32], b = lm[t + i * 32];
            ss.x += a.x; ss.y += a.y;
            mm.x = fmaxf(mm.x, b.x); mm.y = fmaxf(mm.y, b.y);
        }
        pooled[g * 128 + 2 * t]          = ss.x;
        pooled[g * 128 + 2 * t + 1]      = ss.y;
        pooled[g * 128 + 64 + 2 * t]     = mm.x;
        pooled[g * 128 + 64 + 2 * t + 1] = mm.y;
    }
}

__global__ void k_head(const float* __restrict__ pooled, const float* __restrict__ gamma,
                       const float* __restrict__ beta, const float* __restrict__ mean,
                       const float* __restrict__ var, const float* __restrict__ fcw,
                       const float* __restrict__ fcb, float* __restrict__ out) {
    __shared__ float y[128];
    __shared__ float lg[8];
    int g = blockIdx.x, c = threadIdx.x;   // 128 threads
    float p = pooled[g * 128 + c];
    y[c] = (p - mean[c]) * rsqrtf(var[c] + 1e-5f) * gamma[c] + beta[c];
    __syncthreads();
    if (c < NCLSo) {
        float l = fcb[c];
        for (int i = 0; i < 128; ++i) l += y[i] * fcw[i * NCLSo + c];
        lg[c] = l;
    }
    __syncthreads();
    if (c == 0) {
        float m = lg[0];
        for (int j = 1; j < NCLSo; ++j) m = fmaxf(m, lg[j]);
        float se = 0.f;
        for (int j = 0; j < NCLSo; ++j) se += expf(lg[j] - m);
        float lse = m + logf(se);
        for (int j = 0; j < NCLSo; ++j) out[g * NCLSo + j] = lg[j] - lse;
    }
}

// ---------------- launch ----------------

static inline size_t rup(size_t x) { return (x + 255) & ~(size_t)255; }

extern "C" void kernel_launch(void* const* d_in, const int* in_sizes, int n_in,
                              void* d_out, int out_size, void* d_ws, size_t ws_size,
                              hipStream_t stream) {
    const float* x     = (const float*)d_in[0];
    const int*   ei    = (const int*)d_in[1];
    const float* eattr = (const float*)d_in[2];
    const int*   batch = (const int*)d_in[3];
    const float* W1    = (const float*)d_in[4];
    const float* b1    = (const float*)d_in[5];
    const float* W2    = (const float*)d_in[6];
    const float* b2    = (const float*)d_in[7];
    const float* W3    = (const float*)d_in[8];
    const float* b3    = (const float*)d_in[9];
    const float* W4    = (const float*)d_in[10];
    const float* b4    = (const float*)d_in[11];
    const float* gamma = (const float*)d_in[12];
    const float* beta  = (const float*)d_in[13];
    const float* mean  = (const float*)d_in[14];
    const float* var   = (const float*)d_in[15];
    const float* fcw   = (const float*)d_in[16];
    const float* fcb   = (const float*)d_in[17];
    float* out = (float*)d_out;

    char* p = (char*)d_ws;
    auto take = [&](size_t bytes) { char* r = p; p += rup(bytes); return r; };
    int*            deg      = (int*)take((size_t)(Nn + 1) * 4);
    unsigned short* cnt      = (unsigned short*)take((size_t)RBK * Nn * 2);
    unsigned short* lrank    = (unsigned short*)take((size_t)Ne * 2);
    int*            rowstart = (int*)take((size_t)(Nn + 1) * 4);
    int*            bsum     = (int*)take((size_t)NB * 4);
    int*            boff     = (int*)take((size_t)NB * 4);
    uint4*          recs     = (uint4*)take((size_t)Ne * 16);
    unsigned*       hA       = (unsigned*)take((size_t)Nn * 32 * 4);
    unsigned*       hB       = (unsigned*)take((size_t)Nn * 32 * 4);
    float*          W1p      = (float*)take((size_t)NEk * 64 * 64 * 4);
    unsigned short* bhiA     = (unsigned short*)take((size_t)4 * 20480 * 2);
    unsigned short* bloA     = (unsigned short*)take((size_t)4 * 20480 * 2);
    float*          pooled   = (float*)take((size_t)Gg * 128 * 4);
    int*            sg       = (int*)take((size_t)Gg * 4);
    int*            eg       = (int*)take((size_t)Gg * 4);

    k_rankhist<<<RBK, 1024, 0, stream>>>(ei, lrank, cnt);
    k_pad_x<<<(Nn * 32 + 255) / 256, 256, 0, stream>>>(x, hA);
    k_pad_w1<<<(NEk * 64 * 64 + 255) / 256, 256, 0, stream>>>(W1, W1p);
    k_pack_b<<<80, 256, 0, stream>>>(W1p, bhiA,             bloA);
    k_pack_b<<<80, 256, 0, stream>>>(W2,  bhiA + 20480,     bloA + 20480);
    k_pack_b<<<80, 256, 0, stream>>>(W3,  bhiA + 2 * 20480, bloA + 2 * 20480);
    k_pack_b<<<80, 256, 0, stream>>>(W4,  bhiA + 3 * 20480, bloA + 3 * 20480);
    k_colscan<<<NB, 256, 0, stream>>>(cnt, deg);
    k_blocksum<<<NB, 256, 0, stream>>>(deg, bsum);
    k_scanpart<<<1, 256, 0, stream>>>(bsum, boff);
    k_scanfinal<<<NB, 256, 0, stream>>>(deg, boff, rowstart);
    k_place<<<(Ne / 4 + 255) / 256, 256, 0, stream>>>(ei, eattr, rowstart, lrank, cnt,
                                                      (unsigned*)recs);
    k_bounds<<<(Nn + 255) / 256, 256, 0, stream>>>(batch, sg, eg);

    const float* bs[4] = { b1, b2, b3, b4 };
    unsigned* cur = hA;
    unsigned* nxt = hB;
    for (int L = 0; L < 4; ++L) {
        k_layer32<<<(Nn + 31) / 32, 256, 0, stream>>>(
            cur, rowstart, recs, bhiA + (size_t)L * 20480, bloA + (size_t)L * 20480,
            bs[L], nxt);
        unsigned* tmp = cur; cur = nxt; nxt = tmp;
    }

    k_pool<<<Gg, 256, 0, stream>>>(cur, sg, eg, pooled);
    k_head<<<Gg, 128, 0, stream>>>(pooled, gamma, beta, mean, var, fcw, fcb, out);
}

// Round 10
// 446.492 us; speedup vs baseline: 1.2407x; 1.2407x over previous
//
#include <hip/hip_runtime.h>

// GNNML3 forward. R14: (a) revert k_place to R7 scalar 1-edge/thread with REGULAR
// stores — R11's nontemporal scatter evicted recs from L2 and made all 4 k_aggregate
// consumers refetch from HBM (R7 479 -> R11 504 while k_place itself only +5us);
// (b) k_transform -> 32-node tiles: 64-node grid was 782 blocks = 3.05/CU (can't fill
// the machine); 1563 blocks, 21KB LDS. Phase2/3 verbatim from correctness-verified
// k_layer32 (same MFMA order, bit-identical). Fusion abandoned (R8/R13 both regressed).

#define Nn   50000
#define Ne   1600000
#define Gg   128
#define NEk  5
#define NINf 16
#define NCLSo 6
#define NB   196        // ceil((Nn+1)/256)
#define RBK  128        // rank histogram blocks
#define CHK  (Ne / RBK) // 12500 edges per block (exact)

using short8 = __attribute__((ext_vector_type(8))) short;
using f32x4  = __attribute__((ext_vector_type(4))) float;
using f32x2  = __attribute__((ext_vector_type(2))) float;

__device__ __forceinline__ float2 bf2u(unsigned u) {
    return make_float2(__uint_as_float(u << 16), __uint_as_float(u & 0xffff0000u));
}
__device__ __forceinline__ unsigned f2bf(float a, float b) {
    unsigned ua = __float_as_uint(a), ub = __float_as_uint(b);
    ua += 0x7fffu + ((ua >> 16) & 1u);
    ub += 0x7fffu + ((ub >> 16) & 1u);
    return (ua >> 16) | (ub & 0xffff0000u);
}
__device__ __forceinline__ unsigned short f2bf1(float a) {
    unsigned ua = __float_as_uint(a);
    ua += 0x7fffu + ((ua >> 16) & 1u);
    return (unsigned short)(ua >> 16);
}

// packed 2xf32 fma with splat multiplier (backend: v_pk_fma_f32).
__device__ __forceinline__ f32x2 fma2s(float a, f32x2 x, f32x2 c) {
#if __has_builtin(__builtin_elementwise_fma)
    f32x2 av; av.x = a; av.y = a;
    return __builtin_elementwise_fma(av, x, c);
#else
    c.x = fmaf(a, x.x, c.x); c.y = fmaf(a, x.y, c.y);
    return c;
#endif
}

// ---------------- prep kernels ----------------

// x [Nn][16] fp32 -> h0 [Nn][32] uint (bf16x2 pairs, features >=16 zero)
__global__ void k_pad_x(const float* __restrict__ x, unsigned* __restrict__ h0) {
    int i = blockIdx.x * 256 + threadIdx.x;           // over Nn*32
    if (i >= Nn * 32) return;
    int n = i >> 5, p = i & 31;
    int f0 = 2 * p;
    float v0 = (f0 < NINf) ? x[n * NINf + f0] : 0.f;
    float v1 = (f0 + 1 < NINf) ? x[n * NINf + f0 + 1] : 0.f;
    h0[i] = f2bf(v0, v1);
}

__global__ void k_pad_w1(const float* __restrict__ W1, float* __restrict__ W1p) {
    int i = blockIdx.x * 256 + threadIdx.x;           // over 5*64*64
    if (i >= NEk * 64 * 64) return;
    int h = i & 63, f = (i >> 6) & 63, k = i >> 12;
    W1p[i] = (f < NINf) ? W1[(k * NINf + f) * 64 + h] : 0.f;
}

// pack W[320][64] fp32 into MFMA B-fragment layout, split hi/lo bf16.
// layout index: ((nt*10 + kstep)*64 + lane)*8 + j ; k = kstep*32 + (lane>>4)*8 + j,
// col = nt*16 + (lane&15).  20480 elements per layer.
__global__ void k_pack_b(const float* __restrict__ W, unsigned short* __restrict__ bhi,
                         unsigned short* __restrict__ blo) {
    int i = blockIdx.x * 256 + threadIdx.x;
    if (i >= 20480) return;
    int j = i & 7, lane = (i >> 3) & 63, t2 = i >> 9;   // t2 = nt*10+kstep, 0..39
    int nt = t2 / 10, kstep = t2 - nt * 10;
    int k = kstep * 32 + (lane >> 4) * 8 + j;
    int col = nt * 16 + (lane & 15);
    float v = W[k * 64 + col];
    unsigned short hi = f2bf1(v);
    float fhi = __uint_as_float(((unsigned)hi) << 16);
    bhi[i] = hi;
    blo[i] = f2bf1(v - fhi);
}

// LDS-privatized per-block histogram + local rank, single pass, u8x4-packed counts.
// Per-(block,node) count <= max degree (~70) < 255, so no inter-byte carry.
__global__ __launch_bounds__(1024) void k_rankhist(
    const int* __restrict__ ei, unsigned short* __restrict__ lrank,
    unsigned short* __restrict__ cnt /* [RBK][Nn] u16 */) {
    __shared__ unsigned hist[12500];                  // 50 KB: 4 u8 counts per word
    int b = blockIdx.x, t = threadIdx.x;
    int e0 = b * CHK;
    for (int w = t; w < 12500; w += 1024) hist[w] = 0;
    __syncthreads();
    for (int i = t; i < CHK; i += 1024) {
        int d = ei[Ne + e0 + i];
        unsigned sh = 8u * (unsigned)(d & 3);
        unsigned old = atomicAdd(&hist[d >> 2], 1u << sh);
        lrank[e0 + i] = (unsigned short)((old >> sh) & 0xffu);
    }
    __syncthreads();
    unsigned* co = (unsigned*)(cnt + (size_t)b * Nn);  // 4B-aligned (Nn even)
    for (int w = t; w < 12500; w += 1024) {
        unsigned hv = hist[w];
        co[2 * w]     = (hv & 0xffu) | ((hv >> 8) & 0xffu) << 16;
        co[2 * w + 1] = ((hv >> 16) & 0xffu) | (hv >> 24) << 16;
    }
}

// per-node exclusive scan over the RBK block counts (in place) + total deg.
__global__ void k_colscan(unsigned short* __restrict__ cnt, int* __restrict__ deg) {
    int d = blockIdx.x * 256 + threadIdx.x;
    if (d >= Nn) return;
    int s = 0;
#pragma unroll 4
    for (int b = 0; b < RBK; ++b) {
        int t = cnt[(size_t)b * Nn + d];
        cnt[(size_t)b * Nn + d] = (unsigned short)s;   // deg(d) ~<=100, fits u16
        s += t;
    }
    deg[d] = s;
}

// -------- 3-phase exclusive scan of deg[0..Nn] -> rowstart --------

__global__ void k_blocksum(const int* __restrict__ deg, int* __restrict__ bsum) {
    __shared__ int l[256];
    int t = threadIdx.x;
    int i = blockIdx.x * 256 + t;
    l[t] = (i < Nn) ? deg[i] : 0;
    __syncthreads();
    for (int off = 128; off > 0; off >>= 1) {
        if (t < off) l[t] += l[t + off];
        __syncthreads();
    }
    if (t == 0) bsum[blockIdx.x] = l[0];
}

__global__ void k_scanpart(const int* __restrict__ bsum, int* __restrict__ boff) {
    __shared__ int l[256];
    int t = threadIdx.x;
    int v = (t < NB) ? bsum[t] : 0;
    l[t] = v;
    __syncthreads();
    for (int off = 1; off < 256; off <<= 1) {
        int u = (t >= off) ? l[t - off] : 0;
        __syncthreads();
        l[t] += u;
        __syncthreads();
    }
    if (t < NB) boff[t] = l[t] - v;                   // exclusive
}

__global__ void k_scanfinal(const int* __restrict__ deg, const int* __restrict__ boff,
                            int* __restrict__ rowstart) {
    __shared__ int l[256];
    int t = threadIdx.x;
    int i = blockIdx.x * 256 + t;
    int v = (i < Nn) ? deg[i] : 0;
    l[t] = v;
    __syncthreads();
    for (int off = 1; off < 256; off <<= 1) {
        int u = (t >= off) ? l[t - off] : 0;
        __syncthreads();
        l[t] += u;
        __syncthreads();
    }
    if (i <= Nn) rowstart[i] = boff[blockIdx.x] + l[t] - v;
}

// deterministic placement: 16B record {src, bf16 a0..a4} to pos. Regular stores
// (NOT nontemporal: recs is re-read 4x by k_aggregate — keep it L2/L3-warm).
__global__ void k_place(const int* __restrict__ ei, const float* __restrict__ eattr,
                        const int* __restrict__ rowstart,
                        const unsigned short* __restrict__ lrank,
                        const unsigned short* __restrict__ cnt,
                        uint4* __restrict__ recs) {
    int e = blockIdx.x * 256 + threadIdx.x;
    if (e >= Ne) return;
    int d = ei[Ne + e];
    int b = e / CHK;                                   // const div -> magic mul
    int pos = rowstart[d] + cnt[(size_t)b * Nn + d] + lrank[e];
    const float* a = eattr + (size_t)e * 5;
    uint4 rr;
    rr.x = (unsigned)ei[e];
    rr.y = f2bf(a[0], a[1]);
    rr.z = f2bf(a[2], a[3]);
    rr.w = f2bf(a[4], 0.f);
    recs[pos] = rr;
}

// batch is sorted -> segment bounds by boundary detection
__global__ void k_bounds(const int* __restrict__ batch, int* __restrict__ sg,
                         int* __restrict__ eg) {
    int n = blockIdx.x * 256 + threadIdx.x;
    if (n >= Nn) return;
    int g = batch[n];
    if (n == 0) sg[g] = 0;
    else {
        int gp = batch[n - 1];
        if (gp != g) { sg[g] = n; eg[gp] = n; }
    }
    if (n == Nn - 1) eg[g] = Nn;
}

// ---------------- per-layer kernels ----------------

// one wave per node; half-wave (32 lanes) per edge, 2 features (bf16x2) per lane.
// unroll x4 -> 8 edges in flight per wave; 5 v_pk_fma_f32 per edge (bit-identical).
__global__ __launch_bounds__(256) void k_aggregate(
    const unsigned* __restrict__ hin, const int* __restrict__ rowstart,
    const uint4* __restrict__ recs, unsigned* __restrict__ agg) {
    int lane = threadIdx.x & 63;
    int l = lane & 31, half = lane >> 5;
    int node = __builtin_amdgcn_readfirstlane((int)(blockIdx.x * 4 + (threadIdx.x >> 6)));
    int beg = rowstart[node], end = rowstart[node + 1];
    f32x2 c0 = {0.f, 0.f}, c1 = c0, c2 = c0, c3 = c0, c4 = c0;
    int ee = beg;
#define EDGE(E) { \
    uint4 r = recs[(E)]; \
    unsigned hx = hin[(size_t)(int)r.x * 32 + l]; \
    f32x2 xv; xv.x = __uint_as_float(hx << 16); xv.y = __uint_as_float(hx & 0xffff0000u); \
    float A0 = __uint_as_float(r.y << 16), A1 = __uint_as_float(r.y & 0xffff0000u); \
    float A2 = __uint_as_float(r.z << 16), A3 = __uint_as_float(r.z & 0xffff0000u); \
    float A4 = __uint_as_float(r.w << 16); \
    c0 = fma2s(A0, xv, c0); c1 = fma2s(A1, xv, c1); \
    c2 = fma2s(A2, xv, c2); c3 = fma2s(A3, xv, c3); \
    c4 = fma2s(A4, xv, c4); }
    for (; ee + 8 <= end; ee += 8) {
        EDGE(ee + half) EDGE(ee + 2 + half) EDGE(ee + 4 + half) EDGE(ee + 6 + half)
    }
    for (; ee + 2 <= end; ee += 2) { EDGE(ee + half) }
    if (ee < end) { if (half == 0) { EDGE(ee) } }
#undef EDGE
    // fold half 1 into half 0 (xor-butterfly, both halves end with the total)
    c0.x += __shfl(c0.x, lane ^ 32); c0.y += __shfl(c0.y, lane ^ 32);
    c1.x += __shfl(c1.x, lane ^ 32); c1.y += __shfl(c1.y, lane ^ 32);
    c2.x += __shfl(c2.x, lane ^ 32); c2.y += __shfl(c2.y, lane ^ 32);
    c3.x += __shfl(c3.x, lane ^ 32); c3.y += __shfl(c3.y, lane ^ 32);
    c4.x += __shfl(c4.x, lane ^ 32); c4.y += __shfl(c4.y, lane ^ 32);
    if (half == 0) {
        unsigned* o = agg + (size_t)node * 160 + l;
        o[0]   = f2bf(c0.x, c0.y);
        o[32]  = f2bf(c1.x, c1.y);
        o[64]  = f2bf(c2.x, c2.y);
        o[96]  = f2bf(c3.x, c3.y);
        o[128] = f2bf(c4.x, c4.y);
    }
}

// MFMA transform, 32-node tiles (R14): [32 x 320]bf16 x (Whi+Wlo)[320 x 64] + bias,
// relu -> bf16. 256 thr = 4 waves; wave w = col-tile w (cols w*16..+15); acc0 = rows
// 0-15, acc1 = rows 16-31; 10 ksteps x (hi,lo) = 40 MFMA/wave. Grid 1563 (vs 782 at
// 64-tile: 3.05 blk/CU couldn't fill the machine), LDS 20992B. Phase2/3 identical to
// the correctness-verified k_layer32.
#define SPAD 41
__global__ __launch_bounds__(256) void k_transform(
    const uint4* __restrict__ A, const unsigned short* __restrict__ bhi,
    const unsigned short* __restrict__ blo, const float* __restrict__ bias,
    unsigned* __restrict__ outh) {
    __shared__ uint4 smem[32 * SPAD];                  // 20992 B
    int t = threadIdx.x;
    int lane = t & 63, wave = t >> 6;
    int m = lane & 15, quad = lane >> 4;
    int blk = blockIdx.x;

    // stage A tile: 32 rows x 40 uint4 (1280), clamp node for tail block
#pragma unroll
    for (int it = 0; it < 5; ++it) {
        int v = t + it * 256;                          // 0..1279
        int row = v / 40, off = v - row * 40;
        int node = blk * 32 + row;
        if (node >= Nn) node = Nn - 1;
        smem[row * SPAD + off] = A[(size_t)node * 40 + off];
    }
    __syncthreads();

    f32x4 acc0 = {0.f, 0.f, 0.f, 0.f}, acc1 = acc0;
    const uint4* ar0 = smem + m * SPAD + quad;         // rows 0-15
    const uint4* ar1 = smem + (16 + m) * SPAD + quad;  // rows 16-31
    const size_t bbase = (size_t)wave * 5120;          // nt = wave
#pragma unroll 2
    for (int ks = 0; ks < 10; ++ks) {
        short8 a0 = *(const short8*)(ar0 + ks * 4);
        short8 a1 = *(const short8*)(ar1 + ks * 4);
        size_t bb = bbase + ((size_t)ks * 64 + lane) * 8;
        short8 h = *(const short8*)(bhi + bb);
        short8 lo = *(const short8*)(blo + bb);
        acc0 = __builtin_amdgcn_mfma_f32_16x16x32_bf16(a0, h,  acc0, 0, 0, 0);
        acc0 = __builtin_amdgcn_mfma_f32_16x16x32_bf16(a0, lo, acc0, 0, 0, 0);
        acc1 = __builtin_amdgcn_mfma_f32_16x16x32_bf16(a1, h,  acc1, 0, 0, 0);
        acc1 = __builtin_amdgcn_mfma_f32_16x16x32_bf16(a1, lo, acc1, 0, 0, 0);
    }
    __syncthreads();                                   // all waves done reading A

    // C-spill [32 rows][72] fp32. C layout (16x16x32): col=lane&15 (global col =
    // wave*16+m), row=quad*4+reg.
    float* Cs = (float*)smem;
#pragma unroll
    for (int r = 0; r < 4; ++r) {
        int base = (quad * 4 + r) * 72 + wave * 16 + m;
        Cs[base]            = acc0[r];
        Cs[base + 16 * 72]  = acc1[r];
    }
    __syncthreads();

    // pack: row = t>>3 (0..31), grp = t&7 -> 4 bf16-pair slots (one uint4)
    {
        int row = t >> 3, grp = t & 7;
        int node = blk * 32 + row;
        if (node < Nn) {
            const float* cr = Cs + row * 72;
            unsigned o[4];
#pragma unroll
            for (int j = 0; j < 4; ++j) {
                int pp = grp * 4 + j;
                float v0 = fmaxf(cr[2 * pp]     + bias[2 * pp],     0.f);
                float v1 = fmaxf(cr[2 * pp + 1] + bias[2 * pp + 1], 0.f);
                o[j] = f2bf(v0, v1);
            }
            *(uint4*)(outh + (size_t)node * 32 + grp * 4) =
                make_uint4(o[0], o[1], o[2], o[3]);
        }
    }
}

// ---------------- pooling + head ----------------

__global__ __launch_bounds__(256) void k_pool(const unsigned* __restrict__ h,
                                              const int* __restrict__ sg,
                                              const int* __restrict__ eg,
                                              float* __restrict__ pooled) {
    __shared__ float2 ls[256], lm[256];
    int g = blockIdx.x, t = threadIdx.x;
    int p = t & 31, q = t >> 5;                        // 32 feature-pairs x 8 node-strides
    int s = sg[g], e = eg[g];
    float2 sum = {0.f, 0.f}, mx = {0.f, 0.f};          // relu>=0 -> 0 valid max identity
    for (int n = s + q; n < e; n += 8) {
        float2 v = bf2u(h[(size_t)n * 32 + p]);
        sum.x += v.x; sum.y += v.y;
        mx.x = fmaxf(mx.x, v.x); mx.y = fmaxf(mx.y, v.y);
    }
    ls[t] = sum; lm[t] = mx;
    __syncthreads();
    if (t < 32) {
        float2 ss = ls[t], mm = lm[t];
        for (int i = 1; i < 8; ++i) {
            float2 a = ls[t + i * 32], b = lm[t + i * 32];
            ss.x += a.x; ss.y += a.y;
            mm.x = fmaxf(mm.x, b.x); mm.y = fmaxf(mm.y, b.y);
        }
        pooled[g * 128 + 2 * t]          = ss.x;
        pooled[g * 128 + 2 * t + 1]      = ss.y;
        pooled[g * 128 + 64 + 2 * t]     = mm.x;
        pooled[g * 128 + 64 + 2 * t + 1] = mm.y;
    }
}

__global__ void k_head(const float* __restrict__ pooled, const float* __restrict__ gamma,
                       const float* __restrict__ beta, const float* __restrict__ mean,
                       const float* __restrict__ var, const float* __restrict__ fcw,
                       const float* __restrict__ fcb, float* __restrict__ out) {
    __shared__ float y[128];
    __shared__ float lg[8];
    int g = blockIdx.x, c = threadIdx.x;   // 128 threads
    float p = pooled[g * 128 + c];
    y[c] = (p - mean[c]) * rsqrtf(var[c] + 1e-5f) * gamma[c] + beta[c];
    __syncthreads();
    if (c < NCLSo) {
        float l = fcb[c];
        for (int i = 0; i < 128; ++i) l += y[i] * fcw[i * NCLSo + c];
        lg[c] = l;
    }
    __syncthreads();
    if (c == 0) {
        float m = lg[0];
        for (int j = 1; j < NCLSo; ++j) m = fmaxf(m, lg[j]);
        float se = 0.f;
        for (int j = 0; j < NCLSo; ++j) se += expf(lg[j] - m);
        float lse = m + logf(se);
        for (int j = 0; j < NCLSo; ++j) out[g * NCLSo + j] = lg[j] - lse;
    }
}

// ---------------- launch ----------------

static inline size_t rup(size_t x) { return (x + 255) & ~(size_t)255; }

extern "C" void kernel_launch(void* const* d_in, const int* in_sizes, int n_in,
                              void* d_out, int out_size, void* d_ws, size_t ws_size,
                              hipStream_t stream) {
    const float* x     = (const float*)d_in[0];
    const int*   ei    = (const int*)d_in[1];
    const float* eattr = (const float*)d_in[2];
    const int*   batch = (const int*)d_in[3];
    const float* W1    = (const float*)d_in[4];
    const float* b1    = (const float*)d_in[5];
    const float* W2    = (const float*)d_in[6];
    const float* b2    = (const float*)d_in[7];
    const float* W3    = (const float*)d_in[8];
    const float* b3    = (const float*)d_in[9];
    const float* W4    = (const float*)d_in[10];
    const float* b4    = (const float*)d_in[11];
    const float* gamma = (const float*)d_in[12];
    const float* beta  = (const float*)d_in[13];
    const float* mean  = (const float*)d_in[14];
    const float* var   = (const float*)d_in[15];
    const float* fcw   = (const float*)d_in[16];
    const float* fcb   = (const float*)d_in[17];
    float* out = (float*)d_out;

    char* p = (char*)d_ws;
    auto take = [&](size_t bytes) { char* r = p; p += rup(bytes); return r; };
    int*            deg      = (int*)take((size_t)(Nn + 1) * 4);
    unsigned short* cnt      = (unsigned short*)take((size_t)RBK * Nn * 2);
    unsigned short* lrank    = (unsigned short*)take((size_t)Ne * 2);
    int*            rowstart = (int*)take((size_t)(Nn + 1) * 4);
    int*            bsum     = (int*)take((size_t)NB * 4);
    int*            boff     = (int*)take((size_t)NB * 4);
    uint4*          recs     = (uint4*)take((size_t)Ne * 16);
    unsigned*       hA       = (unsigned*)take((size_t)Nn * 32 * 4);
    unsigned*       hB       = (unsigned*)take((size_t)Nn * 32 * 4);
    unsigned*       agg      = (unsigned*)take((size_t)Nn * 160 * 4);
    float*          W1p      = (float*)take((size_t)NEk * 64 * 64 * 4);
    unsigned short* bhiA     = (unsigned short*)take((size_t)4 * 20480 * 2);
    unsigned short* bloA     = (unsigned short*)take((size_t)4 * 20480 * 2);
    float*          pooled   = (float*)take((size_t)Gg * 128 * 4);
    int*            sg       = (int*)take((size_t)Gg * 4);
    int*            eg       = (int*)take((size_t)Gg * 4);

    k_rankhist<<<RBK, 1024, 0, stream>>>(ei, lrank, cnt);
    k_pad_x<<<(Nn * 32 + 255) / 256, 256, 0, stream>>>(x, hA);
    k_pad_w1<<<(NEk * 64 * 64 + 255) / 256, 256, 0, stream>>>(W1, W1p);
    k_pack_b<<<80, 256, 0, stream>>>(W1p, bhiA,             bloA);
    k_pack_b<<<80, 256, 0, stream>>>(W2,  bhiA + 20480,     bloA + 20480);
    k_pack_b<<<80, 256, 0, stream>>>(W3,  bhiA + 2 * 20480, bloA + 2 * 20480);
    k_pack_b<<<80, 256, 0, stream>>>(W4,  bhiA + 3 * 20480, bloA + 3 * 20480);
    k_colscan<<<NB, 256, 0, stream>>>(cnt, deg);
    k_blocksum<<<NB, 256, 0, stream>>>(deg, bsum);
    k_scanpart<<<1, 256, 0, stream>>>(bsum, boff);
    k_scanfinal<<<NB, 256, 0, stream>>>(deg, boff, rowstart);
    k_place<<<(Ne + 255) / 256, 256, 0, stream>>>(ei, eattr, rowstart, lrank, cnt, recs);
    k_bounds<<<(Nn + 255) / 256, 256, 0, stream>>>(batch, sg, eg);

    const float* bs[4] = { b1, b2, b3, b4 };
    unsigned* cur = hA;
    unsigned* nxt = hB;
    for (int L = 0; L < 4; ++L) {
        k_aggregate<<<Nn / 4, 256, 0, stream>>>(cur, rowstart, recs, agg);
        k_transform<<<(Nn + 31) / 32, 256, 0, stream>>>(
            (const uint4*)agg, bhiA + (size_t)L * 20480, bloA + (size_t)L * 20480,
            bs[L], nxt);
        unsigned* tmp = cur; cur = nxt; nxt = tmp;
    }

    k_pool<<<Gg, 256, 0, stream>>>(cur, sg, eg, pooled);
    k_head<<<Gg, 128, 0, stream>>>(pooled, gamma, beta, mean, var, fcw, fcb, out);
}